// Round 2
// baseline (34631.015 us; speedup 1.0000x reference)
//
#include <hip/hip_runtime.h>
#include <hip/hip_bf16.h>
#include <cstdint>
#include <cstddef>

#define V_   4096
#define D_   1024
#define H_   16
#define NL_  12
#define DFF_ 2752
#define DH_  64
#define T_   1365
#define B_   2
#define BT_  (B_ * T_)

static __device__ __forceinline__ int scale_of(int t) {
  return (t < 1) ? 0 : (t < 5) ? 1 : (t < 21) ? 2 : (t < 85) ? 3 : (t < 341) ? 4 : 5;
}
static __device__ __forceinline__ int scale_start(int s) {
  return (s == 0) ? 0 : (s == 1) ? 1 : (s == 2) ? 5 : (s == 3) ? 21 : (s == 4) ? 85 : 341;
}
static __device__ __forceinline__ int scale_end(int s) {
  return (s == 0) ? 1 : (s == 1) ? 5 : (s == 2) ? 21 : (s == 3) ? 85 : (s == 4) ? 341 : 1365;
}

// ---------------- embed: h[b,t,:] = (t==0 ? start : tok_emb[idx]) + scl_emb[scale(t)]
__global__ __launch_bounds__(256) void embed_kernel(
    const int* __restrict__ i0, const int* __restrict__ i1, const int* __restrict__ i2,
    const int* __restrict__ i3, const int* __restrict__ i4, const int* __restrict__ i5,
    const float* __restrict__ tok_emb, const float* __restrict__ scl_emb,
    const float* __restrict__ start_tok, float* __restrict__ h, int* __restrict__ tokens) {
  int row = blockIdx.x;              // b*T + t
  int b = row / T_, t = row % T_;
  int s = scale_of(t);
  int st = scale_start(s);
  int sz = scale_end(s) - st;
  const int* ip = (s == 0) ? i0 : (s == 1) ? i1 : (s == 2) ? i2 : (s == 3) ? i3 : (s == 4) ? i4 : i5;
  int tok = ip[b * sz + (t - st)];
  if (threadIdx.x == 0) tokens[row] = tok;
  const float* base = (t == 0) ? start_tok : (tok_emb + (size_t)tok * D_);
  size_t ho = (size_t)row * D_;
  for (int d = threadIdx.x; d < D_; d += 256)
    h[ho + d] = base[d] + scl_emb[s * D_ + d];
}

// ---------------- generic fp32 GEMM. NT=0: W is [K,N]; NT=1: W is [N,K]
template <int NT>
__global__ __launch_bounds__(256) void gemm_kernel(
    const float* __restrict__ A, const float* __restrict__ W, float* __restrict__ C,
    int M, int N, int K) {
  __shared__ float As[16][68];
  __shared__ float Bs[16][68];
  const int bm = blockIdx.y * 64;
  const int bn = blockIdx.x * 64;
  const int tx = threadIdx.x;
  const int trow = (tx >> 4) << 2;
  const int tcol = (tx & 15) << 2;
  float acc[4][4] = {};
  for (int k0 = 0; k0 < K; k0 += 16) {
    for (int i = tx; i < 64 * 16; i += 256) {
      int m = i >> 4, kk = i & 15;
      int gm = bm + m;
      As[kk][m] = (gm < M) ? A[(size_t)gm * K + (k0 + kk)] : 0.f;
    }
    for (int i = tx; i < 16 * 64; i += 256) {
      if (NT) { int n = i >> 4, kk = i & 15; Bs[kk][n] = W[(size_t)(bn + n) * K + (k0 + kk)]; }
      else    { int kk = i >> 6, n = i & 63; Bs[kk][n] = W[(size_t)(k0 + kk) * N + (bn + n)]; }
    }
    __syncthreads();
#pragma unroll
    for (int kk = 0; kk < 16; ++kk) {
      const float4 af = *(const float4*)(&As[kk][trow]);
      const float4 bf = *(const float4*)(&Bs[kk][tcol]);
      const float a_[4] = {af.x, af.y, af.z, af.w};
      const float b_[4] = {bf.x, bf.y, bf.z, bf.w};
#pragma unroll
      for (int ii = 0; ii < 4; ++ii)
#pragma unroll
        for (int jj = 0; jj < 4; ++jj) acc[ii][jj] += a_[ii] * b_[jj];
    }
    __syncthreads();
  }
#pragma unroll
  for (int ii = 0; ii < 4; ++ii) {
    int gm = bm + trow + ii;
    if (gm < M) {
#pragma unroll
      for (int jj = 0; jj < 4; ++jj) C[(size_t)gm * N + bn + tcol + jj] = acc[ii][jj];
    }
  }
}

// ---------------- per-head RMSNorm + RoPE on q and k, in place. one wave per (b,t,h)
__global__ __launch_bounds__(64) void qkrope_kernel(
    float* __restrict__ q, float* __restrict__ k,
    const float* __restrict__ qn, const float* __restrict__ kn) {
  int g = blockIdx.x;          // (b*T+t)*H + h
  int d = threadIdx.x;         // 0..63
  int bt = g / H_, hh = g % H_;
  int t = bt % T_;
  int s = scale_of(t);
  int pos = t - scale_start(s);
  int j = d & 31;
  float inv = expf(-0.28782313662425574f * (float)j);   // 10000^(-2j/64)
  float ang = (float)pos * inv;
  float c = cosf(ang), sn = sinf(ang);
  size_t off = (size_t)bt * D_ + hh * DH_ + d;

  // q
  {
    float x = q[off];
    float ss = x * x;
#pragma unroll
    for (int m = 32; m; m >>= 1) ss += __shfl_xor(ss, m);
    float r = rsqrtf(ss * (1.f / 64.f) + 1e-6f);
    float xn = x * r * qn[d];
    float part = __shfl_xor(xn, 32);
    q[off] = xn * c + ((d < 32) ? -part : part) * sn;
  }
  // k
  {
    float x = k[off];
    float ss = x * x;
#pragma unroll
    for (int m = 32; m; m >>= 1) ss += __shfl_xor(ss, m);
    float r = rsqrtf(ss * (1.f / 64.f) + 1e-6f);
    float xn = x * r * kn[d];
    float part = __shfl_xor(xn, 32);
    k[off] = xn * c + ((d < 32) ? -part : part) * sn;
  }
}

// ---------------- flash-style prefix attention. block: (q_tile of 16, head, batch)
__global__ __launch_bounds__(256) void attn_kernel(
    const float* __restrict__ q, const float* __restrict__ k,
    const float* __restrict__ v, float* __restrict__ o) {
  __shared__ float Qs[16][68], Ks[16][68], Vs[16][68], Ps[16][16];
  const int qt = blockIdx.x, hh = blockIdx.y, b = blockIdx.z;
  const int tx = threadIdx.x;
  const int qi = tx >> 4;        // local query 0..15
  const int lane = tx & 15;
  const int i = qt * 16 + qi;    // global query

  for (int idx = tx; idx < 16 * 64; idx += 256) {
    int r = idx >> 6, col = idx & 63;
    int gi = qt * 16 + r;
    Qs[r][col] = (gi < T_) ? q[((size_t)(b * T_ + gi)) * D_ + hh * DH_ + col] : 0.f;
  }
  const int e_i = (i < T_) ? scale_end(scale_of(i)) : 0;
  const int last_valid = min(qt * 16 + 15, T_ - 1);
  const int e_max = scale_end(scale_of(last_valid));

  float m = -INFINITY, l = 0.f;
  float o0 = 0.f, o1 = 0.f, o2 = 0.f, o3 = 0.f;

  for (int j0 = 0; j0 < e_max; j0 += 16) {
    __syncthreads();
    for (int idx = tx; idx < 16 * 64; idx += 256) {
      int r = idx >> 6, col = idx & 63;
      int gj = j0 + r;
      bool ok = gj < e_max;
      size_t go = ((size_t)(b * T_ + gj)) * D_ + hh * DH_ + col;
      Ks[r][col] = ok ? k[go] : 0.f;
      Vs[r][col] = ok ? v[go] : 0.f;
    }
    __syncthreads();

    float s = 0.f;
#pragma unroll
    for (int d = 0; d < 64; ++d) s += Qs[qi][d] * Ks[lane][d];
    s *= 0.125f;
    int gj = j0 + lane;
    if (gj >= e_i) s = -INFINITY;

    float tmax = s;
#pragma unroll
    for (int mm = 8; mm; mm >>= 1) tmax = fmaxf(tmax, __shfl_xor(tmax, mm, 16));
    float m_new = fmaxf(m, tmax);
    float alpha, p;
    if (m_new == -INFINITY) { alpha = 1.f; p = 0.f; }
    else {
      alpha = (m == -INFINITY) ? 0.f : expf(m - m_new);
      p = (s == -INFINITY) ? 0.f : expf(s - m_new);
    }
    float psum = p;
#pragma unroll
    for (int mm = 8; mm; mm >>= 1) psum += __shfl_xor(psum, mm, 16);
    l = l * alpha + psum;
    m = m_new;
    Ps[qi][lane] = p;
    __syncthreads();

    o0 *= alpha; o1 *= alpha; o2 *= alpha; o3 *= alpha;
    const int dbase = lane * 4;
#pragma unroll
    for (int jj = 0; jj < 16; ++jj) {
      float pv = Ps[qi][jj];
      o0 += pv * Vs[jj][dbase + 0];
      o1 += pv * Vs[jj][dbase + 1];
      o2 += pv * Vs[jj][dbase + 2];
      o3 += pv * Vs[jj][dbase + 3];
    }
  }
  if (i < T_) {
    float invl = 1.f / l;
    size_t off = ((size_t)(b * T_ + i)) * D_ + hh * DH_ + lane * 4;
    o[off + 0] = o0 * invl;
    o[off + 1] = o1 * invl;
    o[off + 2] = o2 * invl;
    o[off + 3] = o3 * invl;
  }
}

// ---------------- h = rms(h + f) * g, one block per row
__global__ __launch_bounds__(256) void rmsadd_kernel(
    float* __restrict__ h, const float* __restrict__ f, const float* __restrict__ g) {
  int row = blockIdx.x;
  int tx = threadIdx.x;
  size_t base = (size_t)row * D_;
  float x[4];
  float ss = 0.f;
#pragma unroll
  for (int i = 0; i < 4; ++i) {
    int d = tx + 256 * i;
    x[i] = h[base + d] + f[base + d];
    ss += x[i] * x[i];
  }
  __shared__ float red[4];
#pragma unroll
  for (int m = 32; m; m >>= 1) ss += __shfl_xor(ss, m);
  if ((tx & 63) == 0) red[tx >> 6] = ss;
  __syncthreads();
  float tot = red[0] + red[1] + red[2] + red[3];
  float r = rsqrtf(tot * (1.f / (float)D_) + 1e-6f);
#pragma unroll
  for (int i = 0; i < 4; ++i) {
    int d = tx + 256 * i;
    h[base + d] = x[i] * r * g[d];
  }
}

// ---------------- a1 = silu(a1) * a3
__global__ __launch_bounds__(256) void swiglu_kernel(
    float* __restrict__ a1, const float* __restrict__ a3, size_t n) {
  size_t idx = (size_t)blockIdx.x * 256 + threadIdx.x;
  if (idx < n) {
    float x = a1[idx];
    float sig = 1.f / (1.f + expf(-x));
    a1[idx] = x * sig * a3[idx];
  }
}

// ---------------- per-row logsumexp + CE partials
__global__ __launch_bounds__(256) void loss_kernel(
    const float* __restrict__ logits, const int* __restrict__ tokens, float* __restrict__ acc) {
  int row = blockIdx.x;
  int tx = threadIdx.x;
  const float* lr = logits + (size_t)row * V_;
  __shared__ float red[4];

  float mx = -INFINITY;
  for (int jv = tx; jv < V_; jv += 256) mx = fmaxf(mx, lr[jv]);
#pragma unroll
  for (int m = 32; m; m >>= 1) mx = fmaxf(mx, __shfl_xor(mx, m));
  if ((tx & 63) == 0) red[tx >> 6] = mx;
  __syncthreads();
  mx = fmaxf(fmaxf(red[0], red[1]), fmaxf(red[2], red[3]));
  __syncthreads();

  float se = 0.f;
  for (int jv = tx; jv < V_; jv += 256) se += expf(lr[jv] - mx);
#pragma unroll
  for (int m = 32; m; m >>= 1) se += __shfl_xor(se, m);
  if ((tx & 63) == 0) red[tx >> 6] = se;
  __syncthreads();
  se = red[0] + red[1] + red[2] + red[3];

  if (tx == 0) {
    float lse = mx + logf(se);
    float lt = lr[tokens[row]];
    atomicAdd(&acc[0], lse - lt);        // CE numerator
    atomicAdd(&acc[1], lse * lse);       // z-loss numerator
  }
}

__global__ void zero_acc_kernel(float* acc) {
  if (threadIdx.x < 2) acc[threadIdx.x] = 0.f;
}

__global__ void finalize_kernel(const float* __restrict__ acc, float* __restrict__ out) {
  out[0] = acc[0] * (1.f / (float)BT_) + 1e-4f * acc[1] * (1.f / (float)BT_);
}

extern "C" void kernel_launch(void* const* d_in, const int* in_sizes, int n_in,
                              void* d_out, int out_size, void* d_ws, size_t ws_size,
                              hipStream_t stream) {
  const int* i0 = (const int*)d_in[0];
  const int* i1 = (const int*)d_in[1];
  const int* i2 = (const int*)d_in[2];
  const int* i3 = (const int*)d_in[3];
  const int* i4 = (const int*)d_in[4];
  const int* i5 = (const int*)d_in[5];
  const float* temb = (const float*)d_in[6];
  const float* semb = (const float*)d_in[7];
  const float* stok = (const float*)d_in[8];
  const float* wq = (const float*)d_in[9];
  const float* wk = (const float*)d_in[10];
  const float* wv = (const float*)d_in[11];
  const float* wo = (const float*)d_in[12];
  const float* qn = (const float*)d_in[13];
  const float* kn = (const float*)d_in[14];
  const float* n1 = (const float*)d_in[15];
  const float* n2 = (const float*)d_in[16];
  const float* w1 = (const float*)d_in[17];
  const float* w3 = (const float*)d_in[18];
  const float* w2 = (const float*)d_in[19];

  // ---- workspace layout (overlapped; ~71 MB total) ----
  const size_t S  = (size_t)BT_ * D_;     // 2,795,520 floats
  const size_t F  = (size_t)BT_ * DFF_;   // 7,512,960 floats
  float* ws = (float*)d_ws;
  float* h  = ws;                          // [S]
  float* R  = ws + S;                      // union region [2F]
  float* qb   = R;                         // attention phase
  float* kb   = R + S;
  float* vb   = R + 2 * S;
  float* ob   = R + 3 * S;
  float* tmp1 = R + 4 * S;                 // attn out-proj result (4S..5S < 2F)
  float* a1   = R;                         // FFN phase (overlaps qb..vb; tmp1 consumed by then)
  float* a3   = R + F;
  float* tmp2 = R + F;                     // FFN down result (overlays a3, consumed by swiglu)
  float* logits = R;                       // head phase (BT*V = 11.18M < 2F = 15.03M)
  int*   tokens = (int*)(ws + S + 2 * F);
  float* acc    = ws + S + 2 * F + ((BT_ + 15) & ~1);

  dim3 blk(256);
  embed_kernel<<<BT_, blk, 0, stream>>>(i0, i1, i2, i3, i4, i5, temb, semb, stok, h, tokens);

  const int Mb = (BT_ + 63) / 64;   // 43
  for (int l = 0; l < NL_; ++l) {
    const float* wql = wq + (size_t)l * D_ * D_;
    const float* wkl = wk + (size_t)l * D_ * D_;
    const float* wvl = wv + (size_t)l * D_ * D_;
    const float* wol = wo + (size_t)l * D_ * D_;
    const float* w1l = w1 + (size_t)l * D_ * DFF_;
    const float* w3l = w3 + (size_t)l * D_ * DFF_;
    const float* w2l = w2 + (size_t)l * DFF_ * D_;

    gemm_kernel<0><<<dim3(D_ / 64, Mb), blk, 0, stream>>>(h, wql, qb, BT_, D_, D_);
    gemm_kernel<0><<<dim3(D_ / 64, Mb), blk, 0, stream>>>(h, wkl, kb, BT_, D_, D_);
    gemm_kernel<0><<<dim3(D_ / 64, Mb), blk, 0, stream>>>(h, wvl, vb, BT_, D_, D_);
    qkrope_kernel<<<BT_ * H_, dim3(64), 0, stream>>>(qb, kb, qn + (size_t)l * DH_, kn + (size_t)l * DH_);
    attn_kernel<<<dim3((T_ + 15) / 16, H_, B_), blk, 0, stream>>>(qb, kb, vb, ob);
    gemm_kernel<0><<<dim3(D_ / 64, Mb), blk, 0, stream>>>(ob, wol, tmp1, BT_, D_, D_);
    rmsadd_kernel<<<BT_, blk, 0, stream>>>(h, tmp1, n1 + (size_t)l * D_);
    gemm_kernel<0><<<dim3(DFF_ / 64, Mb), blk, 0, stream>>>(h, w1l, a1, BT_, DFF_, D_);
    gemm_kernel<0><<<dim3(DFF_ / 64, Mb), blk, 0, stream>>>(h, w3l, a3, BT_, DFF_, D_);
    {
      size_t n = (size_t)BT_ * DFF_;
      swiglu_kernel<<<(unsigned)((n + 255) / 256), blk, 0, stream>>>(a1, a3, n);
    }
    gemm_kernel<0><<<dim3(D_ / 64, Mb), blk, 0, stream>>>(a1, w2l, tmp2, BT_, D_, DFF_);
    rmsadd_kernel<<<BT_, blk, 0, stream>>>(h, tmp2, n2 + (size_t)l * D_);
  }

  // head: logits = h @ token_embed^T   (NT: W is [V, D])
  gemm_kernel<1><<<dim3(V_ / 64, Mb), blk, 0, stream>>>(h, temb, logits, BT_, V_, D_);
  zero_acc_kernel<<<1, 64, 0, stream>>>(acc);
  loss_kernel<<<BT_, blk, 0, stream>>>(logits, tokens, acc);
  finalize_kernel<<<1, 1, 0, stream>>>(acc, (float*)d_out);
}